// Round 4
// baseline (106.102 us; speedup 1.0000x reference)
//
#include <hip/hip_runtime.h>

#define HW 4096   // 64*64 pixels per (b,c) image

typedef float f4 __attribute__((ext_vector_type(4)));
typedef float f2 __attribute__((ext_vector_type(2)));

#define WSTRIDE 194   // weight LDS row stride (floats): even -> b64-aligned f2 reads,
                      // lane stride 2 -> 2-way bank aliasing (free)

// ---------------------------------------------------------------------------
// proj v4: q=Wq@x, k=Wk@x, v=Wv@y. grid=256 (1/CU), block=256.
// Block = 64 px x all 64 couts x 3 mats. Thread = co-pair (cg) x 8 px (pq).
// Weights LDS-transposed once; per c-iter: 3 ds_read_b64 vs 48 FMAs.
// Epilogue bounces acc through a 192x64 XOR-swizzled LDS tile so global
// stores are coalesced (v3 scattered 16B/lane over 32KB lane stride).
// q,k,v are consecutive 1M-float regions of d_ws -> single base pointer.
// ---------------------------------------------------------------------------
__global__ __launch_bounds__(256) void proj_kernel(
    const float* __restrict__ x, const float* __restrict__ y,
    const float* __restrict__ Wq, const float* __restrict__ Wk,
    const float* __restrict__ Wv,
    float* __restrict__ qkv)    // q | k | v, each 1<<20 floats
{
    __shared__ float lds[64 * WSTRIDE];   // 12416 floats; reused as 192x64 bounce
    const int t = threadIdx.x;

    // stage weights transposed: lds[c][m*64+co]
    {
        const float* Ws[3] = {Wq, Wk, Wv};
#pragma unroll
        for (int m = 0; m < 3; ++m) {
#pragma unroll
            for (int s = 0; s < 4; ++s) {
                const int fi = s * 256 + t;
                const int co = fi >> 4, c4 = fi & 15;
                const f4 w = *(const f4*)&Ws[m][co * 64 + c4 * 4];
#pragma unroll
                for (int i = 0; i < 4; ++i)
                    lds[(c4 * 4 + i) * WSTRIDE + m * 64 + co] = w[i];
            }
        }
    }
    __syncthreads();

    const int cg  = t & 31;          // cout-pair (couts 2cg, 2cg+1)
    const int pq  = t >> 5;          // px-octet 0..7
    const int px0 = blockIdx.x * 64;
    const int b   = px0 >> 12;
    const int poffb = px0 & 4095;
    const int poff  = poffb + pq * 8;
    const float* xb = x + (size_t)b * 64 * HW + poff;
    const float* yb = y + (size_t)b * 64 * HW + poff;

    f4 acc[3][2][2];                 // [mat][co-sub][px-half]
#pragma unroll
    for (int m = 0; m < 3; ++m)
#pragma unroll
        for (int i = 0; i < 2; ++i)
#pragma unroll
            for (int h = 0; h < 2; ++h)
                acc[m][i][h] = (f4){0.f, 0.f, 0.f, 0.f};

#pragma unroll 8
    for (int c = 0; c < 64; ++c) {
        const f4 xv0 = *(const f4*)&xb[c * HW];
        const f4 xv1 = *(const f4*)&xb[c * HW + 4];
        const f4 yv0 = *(const f4*)&yb[c * HW];
        const f4 yv1 = *(const f4*)&yb[c * HW + 4];
        const float* wr = &lds[c * WSTRIDE + 2 * cg];
        const f2 wq = *(const f2*)&wr[0];
        const f2 wk = *(const f2*)&wr[64];
        const f2 wv = *(const f2*)&wr[128];
        acc[0][0][0] += xv0 * wq[0];  acc[0][0][1] += xv1 * wq[0];
        acc[0][1][0] += xv0 * wq[1];  acc[0][1][1] += xv1 * wq[1];
        acc[1][0][0] += xv0 * wk[0];  acc[1][0][1] += xv1 * wk[0];
        acc[1][1][0] += xv0 * wk[1];  acc[1][1][1] += xv1 * wk[1];
        acc[2][0][0] += yv0 * wv[0];  acc[2][0][1] += yv1 * wv[0];
        acc[2][1][0] += yv0 * wv[1];  acc[2][1][1] += yv1 * wv[1];
    }

    __syncthreads();                 // weights no longer needed; reuse lds

    // bounce: row = m*64+co (0..191), chunk = px-quad 0..15, XOR swizzle
#pragma unroll
    for (int m = 0; m < 3; ++m)
#pragma unroll
        for (int i = 0; i < 2; ++i)
#pragma unroll
            for (int h = 0; h < 2; ++h) {
                const int row = m * 64 + 2 * cg + i;
                const int ch  = pq * 2 + h;
                *(f4*)&lds[row * 64 + ((ch ^ (row & 15)) << 2)] = acc[m][i][h];
            }
    __syncthreads();

    // coalesced readback + store: 12 f4 per thread, wave = 4 rows x 256B runs
#pragma unroll
    for (int s = 0; s < 12; ++s) {
        const int fi  = s * 256 + t;
        const int row = fi >> 4, ch = fi & 15;
        const f4 val = *(const f4*)&lds[row * 64 + ((ch ^ (row & 15)) << 2)];
        float* dst = qkv + (size_t)(row >> 6) * (1 << 20)
                         + ((size_t)b * 64 + (row & 63)) * HW + poffb + ch * 4;
        *(f4*)dst = val;
    }
}

// ---------------------------------------------------------------------------
// attn v4: per-channel 7x7 window attention, LDS k/v tile with zero halo.
// Inner op per (element,position): fma + exp2 + add + fma (3 VALU + 1 trans).
// No clamp: |log2e*q*(k+bias)| < ~100 << 128 (fp32 exp2 overflow), tail-safe.
// Bias folded as qb[j][p] = qe[p]*bias[j]; body duplicated under the
// wave-uniform c<32 branch (qb indexed by kh vs kw).
// ---------------------------------------------------------------------------
__global__ __launch_bounds__(256) void attn_kernel(
    const float* __restrict__ qg, const float* __restrict__ kg,
    const float* __restrict__ vg,
    const float* __restrict__ rel_h, const float* __restrict__ rel_w,
    float* __restrict__ out)
{
    __shared__ float kT[22 * 72];
    __shared__ float vT[22 * 72];

    const int blk = blockIdx.x;
    const int bc  = blk >> 2;            // b*64 + c
    const int h0  = (blk & 3) << 4;
    const int c   = bc & 63;
    const int t   = threadIdx.x;

    const float* kimg = kg + (size_t)bc * HW;
    const float* vimg = vg + (size_t)bc * HW;
    const f4 z4 = {0.f, 0.f, 0.f, 0.f};

    if (t < 88) {                        // horizontal halo zero
        const int row = t >> 2, side = (t >> 1) & 1, arr = t & 1;
        float* dst = arr ? vT : kT;
        *(f4*)&dst[row * 72 + side * 68] = z4;
    }
#pragma unroll
    for (int j = 0; j < 2; ++j) {        // interior: 22 rows x 16 f4 chunks
        const int idx = j * 256 + t;
        if (idx < 352) {
            const int row = idx >> 4, ch = idx & 15;
            const int hy = h0 - 3 + row;
            const bool rv = ((unsigned)hy < 64u);
            const f4 kv = rv ? *(const f4*)&kimg[hy * 64 + ch * 4] : z4;
            const f4 vv = rv ? *(const f4*)&vimg[hy * 64 + ch * 4] : z4;
            *(f4*)&kT[row * 72 + ch * 4 + 4] = kv;
            *(f4*)&vT[row * 72 + ch * 4 + 4] = vv;
        }
    }
    __syncthreads();

    const int r  = t >> 4;               // 0..15
    const int w0 = (t & 15) << 2;
    const int h  = h0 + r;

    const float LOG2E = 1.4426950408889634f;
    const f4 qv = *(const f4*)&qg[(size_t)bc * HW + h * 64 + w0];
    float qe[4];
#pragma unroll
    for (int p = 0; p < 4; ++p) qe[p] = qv[p] * LOG2E;

    float qb[7][4];
    if (c < 32) {
#pragma unroll
        for (int a = 0; a < 7; ++a) {
            const float bb = rel_h[c * 7 + a];
#pragma unroll
            for (int p = 0; p < 4; ++p) qb[a][p] = qe[p] * bb;
        }
    } else {
#pragma unroll
        for (int j = 0; j < 7; ++j) {
            const float bb = rel_w[(c - 32) * 7 + j];
#pragma unroll
            for (int p = 0; p < 4; ++p) qb[j][p] = qe[p] * bb;
        }
    }

    float l[4] = {0.f, 0.f, 0.f, 0.f};
    float o[4] = {0.f, 0.f, 0.f, 0.f};

    if (c < 32) {
#pragma unroll
        for (int a = 0; a < 7; ++a) {
            const int ro = (r + a) * 72 + w0;
            const f4 k0 = *(const f4*)&kT[ro];
            const f4 k1 = *(const f4*)&kT[ro + 4];
            const f4 k2 = *(const f4*)&kT[ro + 8];
            const f4 v0 = *(const f4*)&vT[ro];
            const f4 v1 = *(const f4*)&vT[ro + 4];
            const f4 v2 = *(const f4*)&vT[ro + 8];
            const float kw[12] = {k0[0], k0[1], k0[2], k0[3], k1[0], k1[1], k1[2], k1[3],
                                  k2[0], k2[1], k2[2], k2[3]};
            const float vw[12] = {v0[0], v0[1], v0[2], v0[3], v1[0], v1[1], v1[2], v1[3],
                                  v2[0], v2[1], v2[2], v2[3]};
#pragma unroll
            for (int b2 = 0; b2 < 7; ++b2)
#pragma unroll
                for (int p = 0; p < 4; ++p) {
                    const float s = fmaf(qe[p], kw[p + b2 + 1], qb[a][p]);
                    const float e = __builtin_amdgcn_exp2f(s);
                    l[p] += e;
                    o[p] = fmaf(e, vw[p + b2 + 1], o[p]);
                }
        }
    } else {
#pragma unroll
        for (int a = 0; a < 7; ++a) {
            const int ro = (r + a) * 72 + w0;
            const f4 k0 = *(const f4*)&kT[ro];
            const f4 k1 = *(const f4*)&kT[ro + 4];
            const f4 k2 = *(const f4*)&kT[ro + 8];
            const f4 v0 = *(const f4*)&vT[ro];
            const f4 v1 = *(const f4*)&vT[ro + 4];
            const f4 v2 = *(const f4*)&vT[ro + 8];
            const float kw[12] = {k0[0], k0[1], k0[2], k0[3], k1[0], k1[1], k1[2], k1[3],
                                  k2[0], k2[1], k2[2], k2[3]};
            const float vw[12] = {v0[0], v0[1], v0[2], v0[3], v1[0], v1[1], v1[2], v1[3],
                                  v2[0], v2[1], v2[2], v2[3]};
#pragma unroll
            for (int b2 = 0; b2 < 7; ++b2)
#pragma unroll
                for (int p = 0; p < 4; ++p) {
                    const float s = fmaf(qe[p], kw[p + b2 + 1], qb[b2][p]);
                    const float e = __builtin_amdgcn_exp2f(s);
                    l[p] += e;
                    o[p] = fmaf(e, vw[p + b2 + 1], o[p]);
                }
        }
    }

    f4 res;
#pragma unroll
    for (int p = 0; p < 4; ++p)
        res[p] = o[p] * __builtin_amdgcn_rcpf(l[p]);
    *(f4*)&out[(size_t)bc * HW + h * 64 + w0] = res;
}

// ---------------------------------------------------------------------------
extern "C" void kernel_launch(void* const* d_in, const int* in_sizes, int n_in,
                              void* d_out, int out_size, void* d_ws, size_t ws_size,
                              hipStream_t stream) {
    const float* x   = (const float*)d_in[0];
    const float* y   = (const float*)d_in[1];
    const float* Wq  = (const float*)d_in[2];
    const float* Wk  = (const float*)d_in[3];
    const float* Wv  = (const float*)d_in[4];
    const float* rlh = (const float*)d_in[5];
    const float* rlw = (const float*)d_in[6];
    float* out = (float*)d_out;

    float* qkv = (float*)d_ws;        // q | k | v, 4 MB each, contiguous
    float* q = qkv;
    float* k = qkv + (1 << 20);
    float* v = qkv + (2 << 20);

    proj_kernel<<<256, 256, 0, stream>>>(x, y, Wq, Wk, Wv, qkv);
    attn_kernel<<<1024, 256, 0, stream>>>(q, k, v, rlh, rlw, out);
}

// Round 5
// 104.237 us; speedup vs baseline: 1.0179x; 1.0179x over previous
//
#include <hip/hip_runtime.h>

#define HW 4096   // 64*64 pixels per (b,c) image

typedef float f4 __attribute__((ext_vector_type(4)));

// ---------------------------------------------------------------------------
// proj v5: q=Wq@x, k=Wk@x, v=Wv@y — scalar-pipe weights, burst x loads.
// grid = 3072 single-wave blocks (256 px-chunks x 12 m-aligned out-splits),
// 3 waves/SIMD. Wave: lane=px (64 px), 16 couts of one matrix.
// Phase 1: 64 independent global loads fill xv[64] (one amortized vmcnt).
// Phase 2: per cout, s_load the contiguous 64-float weight row into SGPRs
// (wave-uniform address -> scalar pipe), 64 v_fmac with scalar operand.
// No LDS at all: kills the v3/v4 LDS-pipe bottleneck (3 ds_read_b64 per
// 24 FMA = 2x oversubscribed per-CU LDS pipe, VALUBusy was 7-9%).
// ---------------------------------------------------------------------------
__global__ __launch_bounds__(64) void proj_kernel(
    const float* __restrict__ x, const float* __restrict__ y,
    const float* __restrict__ Wq, const float* __restrict__ Wk,
    const float* __restrict__ Wv,
    float* __restrict__ qkv)     // q | k | v, each 1<<20 floats
{
    const int blk = blockIdx.x;
    const int pc  = blk & 255;           // px-chunk 0..255
    const int sp  = blk >> 8;            // out-split 0..11
    const int m   = sp >> 2;             // 0=q (x), 1=k (x), 2=v (y)
    const int cb  = (sp & 3) << 4;       // cout base within matrix
    const int px  = pc * 64 + threadIdx.x;
    const int b   = px >> 12;
    const int pp  = px & 4095;

    const float* W   = (m == 0) ? Wq : (m == 1) ? Wk : Wv;   // uniform
    const float* src = (m == 2) ? y : x;                     // uniform
    const float* sb  = src + (size_t)b * 64 * HW + pp;

    // Phase 1: burst-load this lane's full input column (64 loads in flight)
    float xv[64];
#pragma unroll
    for (int c = 0; c < 64; ++c)
        xv[c] = sb[c * HW];

    // Phase 2: 16 couts; weight row is wave-uniform -> SGPRs via s_load
    float* dstm = qkv + (size_t)m * (1 << 20) + (size_t)b * 64 * HW + pp;
#pragma unroll
    for (int i = 0; i < 16; ++i) {
        const float* wr = W + (cb + i) * 64;   // contiguous 256B, uniform
        float acc = 0.f;
#pragma unroll
        for (int c = 0; c < 64; ++c)
            acc = fmaf(wr[c], xv[c], acc);
        dstm[(size_t)(cb + i) * HW] = acc;
    }
}

// ---------------------------------------------------------------------------
// attn v4 (unchanged): per-channel 7x7 window attention, LDS k/v tile with
// zero halo. Inner op per (element,position): fma + exp2 + add + fma.
// No clamp: |log2e*q*(k+bias)| < ~100 << 128 (fp32 exp2 overflow), tail-safe.
// ---------------------------------------------------------------------------
__global__ __launch_bounds__(256) void attn_kernel(
    const float* __restrict__ qg, const float* __restrict__ kg,
    const float* __restrict__ vg,
    const float* __restrict__ rel_h, const float* __restrict__ rel_w,
    float* __restrict__ out)
{
    __shared__ float kT[22 * 72];
    __shared__ float vT[22 * 72];

    const int blk = blockIdx.x;
    const int bc  = blk >> 2;            // b*64 + c
    const int h0  = (blk & 3) << 4;
    const int c   = bc & 63;
    const int t   = threadIdx.x;

    const float* kimg = kg + (size_t)bc * HW;
    const float* vimg = vg + (size_t)bc * HW;
    const f4 z4 = {0.f, 0.f, 0.f, 0.f};

    if (t < 88) {                        // horizontal halo zero
        const int row = t >> 2, side = (t >> 1) & 1, arr = t & 1;
        float* dst = arr ? vT : kT;
        *(f4*)&dst[row * 72 + side * 68] = z4;
    }
#pragma unroll
    for (int j = 0; j < 2; ++j) {        // interior: 22 rows x 16 f4 chunks
        const int idx = j * 256 + t;
        if (idx < 352) {
            const int row = idx >> 4, ch = idx & 15;
            const int hy = h0 - 3 + row;
            const bool rv = ((unsigned)hy < 64u);
            const f4 kv = rv ? *(const f4*)&kimg[hy * 64 + ch * 4] : z4;
            const f4 vv = rv ? *(const f4*)&vimg[hy * 64 + ch * 4] : z4;
            *(f4*)&kT[row * 72 + ch * 4 + 4] = kv;
            *(f4*)&vT[row * 72 + ch * 4 + 4] = vv;
        }
    }
    __syncthreads();

    const int r  = t >> 4;               // 0..15
    const int w0 = (t & 15) << 2;
    const int h  = h0 + r;

    const float LOG2E = 1.4426950408889634f;
    const f4 qv = *(const f4*)&qg[(size_t)bc * HW + h * 64 + w0];
    float qe[4];
#pragma unroll
    for (int p = 0; p < 4; ++p) qe[p] = qv[p] * LOG2E;

    float qb[7][4];
    if (c < 32) {
#pragma unroll
        for (int a = 0; a < 7; ++a) {
            const float bb = rel_h[c * 7 + a];
#pragma unroll
            for (int p = 0; p < 4; ++p) qb[a][p] = qe[p] * bb;
        }
    } else {
#pragma unroll
        for (int j = 0; j < 7; ++j) {
            const float bb = rel_w[(c - 32) * 7 + j];
#pragma unroll
            for (int p = 0; p < 4; ++p) qb[j][p] = qe[p] * bb;
        }
    }

    float l[4] = {0.f, 0.f, 0.f, 0.f};
    float o[4] = {0.f, 0.f, 0.f, 0.f};

    if (c < 32) {
#pragma unroll
        for (int a = 0; a < 7; ++a) {
            const int ro = (r + a) * 72 + w0;
            const f4 k0 = *(const f4*)&kT[ro];
            const f4 k1 = *(const f4*)&kT[ro + 4];
            const f4 k2 = *(const f4*)&kT[ro + 8];
            const f4 v0 = *(const f4*)&vT[ro];
            const f4 v1 = *(const f4*)&vT[ro + 4];
            const f4 v2 = *(const f4*)&vT[ro + 8];
            const float kw[12] = {k0[0], k0[1], k0[2], k0[3], k1[0], k1[1], k1[2], k1[3],
                                  k2[0], k2[1], k2[2], k2[3]};
            const float vw[12] = {v0[0], v0[1], v0[2], v0[3], v1[0], v1[1], v1[2], v1[3],
                                  v2[0], v2[1], v2[2], v2[3]};
#pragma unroll
            for (int b2 = 0; b2 < 7; ++b2)
#pragma unroll
                for (int p = 0; p < 4; ++p) {
                    const float s = fmaf(qe[p], kw[p + b2 + 1], qb[a][p]);
                    const float e = __builtin_amdgcn_exp2f(s);
                    l[p] += e;
                    o[p] = fmaf(e, vw[p + b2 + 1], o[p]);
                }
        }
    } else {
#pragma unroll
        for (int a = 0; a < 7; ++a) {
            const int ro = (r + a) * 72 + w0;
            const f4 k0 = *(const f4*)&kT[ro];
            const f4 k1 = *(const f4*)&kT[ro + 4];
            const f4 k2 = *(const f4*)&kT[ro + 8];
            const f4 v0 = *(const f4*)&vT[ro];
            const f4 v1 = *(const f4*)&vT[ro + 4];
            const f4 v2 = *(const f4*)&vT[ro + 8];
            const float kw[12] = {k0[0], k0[1], k0[2], k0[3], k1[0], k1[1], k1[2], k1[3],
                                  k2[0], k2[1], k2[2], k2[3]};
            const float vw[12] = {v0[0], v0[1], v0[2], v0[3], v1[0], v1[1], v1[2], v1[3],
                                  v2[0], v2[1], v2[2], v2[3]};
#pragma unroll
            for (int b2 = 0; b2 < 7; ++b2)
#pragma unroll
                for (int p = 0; p < 4; ++p) {
                    const float s = fmaf(qe[p], kw[p + b2 + 1], qb[b2][p]);
                    const float e = __builtin_amdgcn_exp2f(s);
                    l[p] += e;
                    o[p] = fmaf(e, vw[p + b2 + 1], o[p]);
                }
        }
    }

    f4 res;
#pragma unroll
    for (int p = 0; p < 4; ++p)
        res[p] = o[p] * __builtin_amdgcn_rcpf(l[p]);
    *(f4*)&out[(size_t)bc * HW + h * 64 + w0] = res;
}

// ---------------------------------------------------------------------------
extern "C" void kernel_launch(void* const* d_in, const int* in_sizes, int n_in,
                              void* d_out, int out_size, void* d_ws, size_t ws_size,
                              hipStream_t stream) {
    const float* x   = (const float*)d_in[0];
    const float* y   = (const float*)d_in[1];
    const float* Wq  = (const float*)d_in[2];
    const float* Wk  = (const float*)d_in[3];
    const float* Wv  = (const float*)d_in[4];
    const float* rlh = (const float*)d_in[5];
    const float* rlw = (const float*)d_in[6];
    float* out = (float*)d_out;

    float* qkv = (float*)d_ws;        // q | k | v, 4 MB each, contiguous
    float* q = qkv;
    float* k = qkv + (1 << 20);
    float* v = qkv + (2 << 20);

    proj_kernel<<<3072, 64, 0, stream>>>(x, y, Wq, Wk, Wv, qkv);
    attn_kernel<<<1024, 256, 0, stream>>>(q, k, v, rlh, rlw, out);
}